// Round 1
// baseline (1651.973 us; speedup 1.0000x reference)
//
#include <hip/hip_runtime.h>
#include <hip/hip_bf16.h>
#include <math.h>

#define N_NODES 100000
#define N_EDGESC 100000
#define NNZ_C   3200000
#define D_IN    512
#define D_HID   16
#define N_CLS   7

// ---------------- setup kernels ----------------

__global__ void count_kernel(const int* __restrict__ nidx, int* __restrict__ cnt, int n) {
  int i = blockIdx.x * blockDim.x + threadIdx.x;
  if (i < n) atomicAdd(&cnt[nidx[i]], 1);
}

// eoff[e] = first i with eidx[i] >= e (eidx sorted); eoff[E] = nnz
__global__ void eoff_kernel(const int* __restrict__ eidx, int* __restrict__ eoff, int nnz, int E) {
  int i = blockIdx.x * blockDim.x + threadIdx.x;
  if (i >= nnz) return;
  int ec = eidx[i];
  int ep = (i == 0) ? -1 : eidx[i - 1];
  for (int e = ep + 1; e <= ec; ++e) eoff[e] = i;
  if (i == nnz - 1) {
    for (int e = ec + 1; e <= E; ++e) eoff[e] = nnz;
  }
}

// single-block exclusive scan: off[0..n-1] = exclusive prefix of cnt, off[n] = total
__global__ void scan_kernel(const int* __restrict__ cnt, int* __restrict__ off, int n) {
  __shared__ int lds[1024];
  int t = threadIdx.x;
  int chunk = (n + 1023) >> 10;
  int base = t * chunk;
  int s = 0;
  for (int k = 0; k < chunk; ++k) { int id = base + k; if (id < n) s += cnt[id]; }
  lds[t] = s;
  __syncthreads();
  for (int d = 1; d < 1024; d <<= 1) {
    int v = (t >= d) ? lds[t - d] : 0;
    __syncthreads();
    lds[t] += v;
    __syncthreads();
  }
  int run = (t == 0) ? 0 : lds[t - 1];
  for (int k = 0; k < chunk; ++k) {
    int id = base + k;
    if (id < n) { off[id] = run; run += cnt[id]; }
  }
  if (t == 1023) off[n] = lds[1023];
}

__global__ void scatter_kernel(const int* __restrict__ nidx, const int* __restrict__ noff,
                               int* __restrict__ cur, int* __restrict__ perm, int n) {
  int i = blockIdx.x * blockDim.x + threadIdx.x;
  if (i >= n) return;
  int v = nidx[i];
  int p = atomicAdd(&cur[v], 1);
  perm[noff[v] + p] = i;
}

// ---------------- GEMM1: h = X[100000,512] @ W[512,16] ----------------
// wave = 4 rows x 16 cols; lane (r4, j). W transposed in LDS, pad 516 -> 2-way bank alias (free).
__global__ void gemm1_kernel(const float* __restrict__ X, const float* __restrict__ W,
                             float* __restrict__ Hout, int N) {
  __shared__ float Wt[16 * 516];
  for (int idx = threadIdx.x; idx < D_IN * 16; idx += blockDim.x) {
    int k = idx >> 4, j = idx & 15;
    Wt[j * 516 + k] = W[idx];
  }
  __syncthreads();
  int wave = (blockIdx.x * blockDim.x + threadIdx.x) >> 6;
  int lane = threadIdx.x & 63;
  int r4 = lane >> 4, j = lane & 15;
  long row = (long)wave * 4 + r4;
  if (row >= N) return;
  const float4* X4 = (const float4*)(X + row * D_IN);
  const float4* w4 = (const float4*)(&Wt[j * 516]);
  float acc = 0.f;
#pragma unroll 8
  for (int kb = 0; kb < D_IN / 4; ++kb) {
    float4 x = X4[kb];
    float4 w = w4[kb];
    acc += x.x * w.x + x.y * w.y + x.z * w.z + x.w * w.w;
  }
  Hout[row * 16 + j] = acc;
}

// ---------------- GEMM2: h2 = elu(H1)[100000,16] @ W2[16,7] ----------------
__global__ void gemm2_kernel(const float* __restrict__ H1, const float* __restrict__ W2,
                             float* __restrict__ h2, int N) {
  __shared__ float w[D_HID * N_CLS];
  if (threadIdx.x < D_HID * N_CLS) w[threadIdx.x] = W2[threadIdx.x];
  __syncthreads();
  int v = blockIdx.x * blockDim.x + threadIdx.x;
  if (v >= N) return;
  const float4* h4 = (const float4*)(H1 + (size_t)v * D_HID);
  float x[16];
#pragma unroll
  for (int q = 0; q < 4; ++q) {
    float4 f = h4[q];
    x[q * 4 + 0] = f.x; x[q * 4 + 1] = f.y; x[q * 4 + 2] = f.z; x[q * 4 + 3] = f.w;
  }
#pragma unroll
  for (int k = 0; k < 16; ++k) x[k] = x[k] > 0.f ? x[k] : expm1f(x[k]);
#pragma unroll
  for (int jj = 0; jj < N_CLS; ++jj) {
    float acc = 0.f;
#pragma unroll
    for (int k = 0; k < 16; ++k) acc += x[k] * w[k * N_CLS + jj];
    h2[(size_t)v * N_CLS + jj] = acc;
  }
}

// ---------------- edge phase: segment softmax over sorted edge_idx ----------------
// one wave per edge; 64 lanes = (64/GROUP) entry-groups x GROUP dims
template <int D, int GROUP>
__global__ void edge_phase(const float* __restrict__ h, const float* __restrict__ a1,
                           const int* __restrict__ eoff, const int* __restrict__ nidx,
                           float* __restrict__ eout, int E) {
  constexpr int NG = 64 / GROUP;
  int wave = (blockIdx.x * blockDim.x + threadIdx.x) >> 6;
  int lane = threadIdx.x & 63;
  int g = lane / GROUP, t = lane % GROUP;
  if (wave >= E) return;
  int o0 = eoff[wave], o1 = eoff[wave + 1];
  float a1v = (t < D) ? a1[t] : 0.f;
  // pass 1: segment max of leaky(hv . a1)
  float m = -INFINITY;
  for (int i = o0 + g; i < o1; i += NG) {
    int v = nidx[i];
    float hv = (t < D) ? h[(size_t)v * D + t] : 0.f;
    float p = hv * a1v;
#pragma unroll
    for (int d = 1; d < GROUP; d <<= 1) p += __shfl_xor(p, d);
    float s = p > 0.f ? p : 0.2f * p;
    m = fmaxf(m, s);
  }
#pragma unroll
  for (int d = GROUP; d < 64; d <<= 1) m = fmaxf(m, __shfl_xor(m, d));
  // pass 2: exp-sum and weighted accumulate
  float lsum = 0.f, acc = 0.f;
  for (int i = o0 + g; i < o1; i += NG) {
    int v = nidx[i];
    float hv = (t < D) ? h[(size_t)v * D + t] : 0.f;
    float p = hv * a1v;
#pragma unroll
    for (int d = 1; d < GROUP; d <<= 1) p += __shfl_xor(p, d);
    float s = p > 0.f ? p : 0.2f * p;
    float ex = __expf(s - m);
    lsum += ex;
    acc += ex * hv;
  }
#pragma unroll
  for (int d = GROUP; d < 64; d <<= 1) {
    lsum += __shfl_xor(lsum, d);
    acc += __shfl_xor(acc, d);
  }
  if (g == 0 && t < D) eout[(size_t)wave * D + t] = acc / (lsum + 1e-9f);
}

// ---------------- node phase: segment softmax over node_idx via CSR perm ----------------
template <int D, int GROUP>
__global__ void node_phase(const float* __restrict__ h, const float* __restrict__ eout,
                           const float* __restrict__ a2, const int* __restrict__ noff,
                           const int* __restrict__ perm, const int* __restrict__ eidx,
                           float* __restrict__ out, int N) {
  constexpr int NG = 64 / GROUP;
  int wave = (blockIdx.x * blockDim.x + threadIdx.x) >> 6;
  int lane = threadIdx.x & 63;
  int g = lane / GROUP, t = lane % GROUP;
  if (wave >= N) return;
  int o0 = noff[wave], o1 = noff[wave + 1];
  float a2h = (t < D) ? a2[t] : 0.f;
  float a2e = (t < D) ? a2[D + t] : 0.f;
  // hv == h[wave] for every entry of this node: compute hv . a2[:D] once
  float ph = ((t < D) ? h[(size_t)wave * D + t] : 0.f) * a2h;
#pragma unroll
  for (int d = 1; d < GROUP; d <<= 1) ph += __shfl_xor(ph, d);
  // pass 1: max
  float m = -INFINITY;
  for (int i = o0 + g; i < o1; i += NG) {
    int idx = perm[i];
    int e = eidx[idx];
    float ev = (t < D) ? eout[(size_t)e * D + t] : 0.f;
    float p = ev * a2e;
#pragma unroll
    for (int d = 1; d < GROUP; d <<= 1) p += __shfl_xor(p, d);
    float s = ph + p;
    s = s > 0.f ? s : 0.2f * s;
    m = fmaxf(m, s);
  }
#pragma unroll
  for (int d = GROUP; d < 64; d <<= 1) m = fmaxf(m, __shfl_xor(m, d));
  // pass 2
  float lsum = 0.f, acc = 0.f;
  for (int i = o0 + g; i < o1; i += NG) {
    int idx = perm[i];
    int e = eidx[idx];
    float ev = (t < D) ? eout[(size_t)e * D + t] : 0.f;
    float p = ev * a2e;
#pragma unroll
    for (int d = 1; d < GROUP; d <<= 1) p += __shfl_xor(p, d);
    float s = ph + p;
    s = s > 0.f ? s : 0.2f * s;
    float ex = __expf(s - m);
    lsum += ex;
    acc += ex * ev;
  }
#pragma unroll
  for (int d = GROUP; d < 64; d <<= 1) {
    lsum += __shfl_xor(lsum, d);
    acc += __shfl_xor(acc, d);
  }
  if (g == 0 && t < D) out[(size_t)wave * D + t] = acc / (lsum + 1e-9f);
}

// ---------------- log_softmax over 7 classes ----------------
__global__ void logsm_kernel(const float* __restrict__ H2, float* __restrict__ logp, int N) {
  int v = blockIdx.x * blockDim.x + threadIdx.x;
  if (v >= N) return;
  float x[N_CLS];
#pragma unroll
  for (int j = 0; j < N_CLS; ++j) x[j] = H2[(size_t)v * N_CLS + j];
  float m = x[0];
#pragma unroll
  for (int j = 1; j < N_CLS; ++j) m = fmaxf(m, x[j]);
  float s = 0.f;
#pragma unroll
  for (int j = 0; j < N_CLS; ++j) s += __expf(x[j] - m);
  float l = logf(s);
#pragma unroll
  for (int j = 0; j < N_CLS; ++j) logp[(size_t)v * N_CLS + j] = x[j] - m - l;
}

// ---------------- launch ----------------

extern "C" void kernel_launch(void* const* d_in, const int* in_sizes, int n_in,
                              void* d_out, int out_size, void* d_ws, size_t ws_size,
                              hipStream_t stream) {
  const float* H    = (const float*)d_in[0];
  const float* W1   = (const float*)d_in[1];
  const float* a1_1 = (const float*)d_in[2];
  const float* a2_1 = (const float*)d_in[3];
  const float* W2   = (const float*)d_in[4];
  const float* a1_2 = (const float*)d_in[5];
  const float* a2_2 = (const float*)d_in[6];
  const int* nidx   = (const int*)d_in[7];
  const int* eidx   = (const int*)d_in[8];

  float* outp = (float*)d_out;
  float* logp = outp;                                   // [N,7]
  float* H1   = outp + (size_t)N_NODES * N_CLS;         // [N,16]
  float* H2   = H1 + (size_t)N_NODES * D_HID;           // [N,7]

  char* ws = (char*)d_ws;
  float* h1g = (float*)(ws + 0);          //  6,400,000 B : N x 16
  float* e1  = (float*)(ws + 6400000);    //  6,400,000 B : E x 16
  float* h2g = (float*)(ws + 12800000);   //  2,800,000 B : N x 7
  float* e2  = (float*)(ws + 15600000);   //  2,800,000 B : E x 7
  int* eoff  = (int*)(ws + 18400000);     //    400,004 B : E+1
  int* noff  = (int*)(ws + 18800128);     //    400,004 B : N+1
  int* ncnt  = (int*)(ws + 19200256);     //    400,000 B : N
  int* perm  = (int*)(ws + 19600384);     // 12,800,000 B : NNZ

  const int TB = 256;
  const int nnz_blocks = (NNZ_C + TB - 1) / TB;

  // CSR by node (built once, reused by both layers)
  hipMemsetAsync(ncnt, 0, N_NODES * sizeof(int), stream);
  count_kernel<<<nnz_blocks, TB, 0, stream>>>(nidx, ncnt, NNZ_C);
  eoff_kernel<<<nnz_blocks, TB, 0, stream>>>(eidx, eoff, NNZ_C, N_EDGESC);
  scan_kernel<<<1, 1024, 0, stream>>>(ncnt, noff, N_NODES);
  hipMemsetAsync(ncnt, 0, N_NODES * sizeof(int), stream);
  scatter_kernel<<<nnz_blocks, TB, 0, stream>>>(nidx, noff, ncnt, perm, NNZ_C);

  // layer 1 (D=16)
  {
    int waves = (N_NODES + 3) / 4;
    int blocks = (waves + 3) / 4;
    gemm1_kernel<<<blocks, TB, 0, stream>>>(H, W1, h1g, N_NODES);
  }
  edge_phase<D_HID, 16><<<(N_EDGESC + 3) / 4, TB, 0, stream>>>(h1g, a1_1, eoff, nidx, e1, N_EDGESC);
  node_phase<D_HID, 16><<<(N_NODES + 3) / 4, TB, 0, stream>>>(h1g, e1, a2_1, noff, perm, eidx, H1, N_NODES);

  // layer 2 (D=7)
  gemm2_kernel<<<(N_NODES + TB - 1) / TB, TB, 0, stream>>>(H1, W2, h2g, N_NODES);
  edge_phase<N_CLS, 8><<<(N_EDGESC + 3) / 4, TB, 0, stream>>>(h2g, a1_2, eoff, nidx, e2, N_EDGESC);
  node_phase<N_CLS, 8><<<(N_NODES + 3) / 4, TB, 0, stream>>>(h2g, e2, a2_2, noff, perm, eidx, H2, N_NODES);

  logsm_kernel<<<(N_NODES + TB - 1) / TB, TB, 0, stream>>>(H2, logp, N_NODES);
}

// Round 2
// 1274.124 us; speedup vs baseline: 1.2966x; 1.2966x over previous
//
#include <hip/hip_runtime.h>
#include <hip/hip_bf16.h>
#include <math.h>

#define N_NODES 100000
#define N_EDGESC 100000
#define NNZ_C   3200000
#define D_IN    512
#define D_HID   16
#define N_CLS   7

// ---------------- setup kernels ----------------

__global__ void count_kernel(const int* __restrict__ nidx, int* __restrict__ cnt, int n) {
  int i = blockIdx.x * blockDim.x + threadIdx.x;
  if (i < n) atomicAdd(&cnt[nidx[i]], 1);
}

// eoff[e] = first i with eidx[i] >= e (eidx sorted); eoff[E] = nnz
__global__ void eoff_kernel(const int* __restrict__ eidx, int* __restrict__ eoff, int nnz, int E) {
  int i = blockIdx.x * blockDim.x + threadIdx.x;
  if (i >= nnz) return;
  int ec = eidx[i];
  int ep = (i == 0) ? -1 : eidx[i - 1];
  for (int e = ep + 1; e <= ec; ++e) eoff[e] = i;
  if (i == nnz - 1) {
    for (int e = ec + 1; e <= E; ++e) eoff[e] = nnz;
  }
}

// single-block exclusive scan
__global__ void scan_kernel(const int* __restrict__ cnt, int* __restrict__ off, int n) {
  __shared__ int lds[1024];
  int t = threadIdx.x;
  int chunk = (n + 1023) >> 10;
  int base = t * chunk;
  int s = 0;
  for (int k = 0; k < chunk; ++k) { int id = base + k; if (id < n) s += cnt[id]; }
  lds[t] = s;
  __syncthreads();
  for (int d = 1; d < 1024; d <<= 1) {
    int v = (t >= d) ? lds[t - d] : 0;
    __syncthreads();
    lds[t] += v;
    __syncthreads();
  }
  int run = (t == 0) ? 0 : lds[t - 1];
  for (int k = 0; k < chunk; ++k) {
    int id = base + k;
    if (id < n) { off[id] = run; run += cnt[id]; }
  }
  if (t == 1023) off[n] = lds[1023];
}

// store the EDGE ID directly into the CSR slot (kills one indirection)
__global__ void scatter_kernel(const int* __restrict__ nidx, const int* __restrict__ eidx,
                               const int* __restrict__ noff,
                               int* __restrict__ cur, int* __restrict__ perm_e, int n) {
  int i = blockIdx.x * blockDim.x + threadIdx.x;
  if (i >= n) return;
  int v = nidx[i];
  int p = atomicAdd(&cur[v], 1);
  perm_e[noff[v] + p] = eidx[i];
}

// ---------------- GEMM1: h = X[100000,512] @ W[512,16]  (+ phv epilogue) ----------------
// wave = 4 rows x 16 cols; lane (r4, j). W transposed in LDS, pad 516.
__global__ void gemm1_kernel(const float* __restrict__ X, const float* __restrict__ W,
                             const float* __restrict__ a1, const float* __restrict__ a2,
                             float* __restrict__ Hout, float2* __restrict__ phv, int N) {
  __shared__ float Wt[16 * 516];
  for (int idx = threadIdx.x; idx < D_IN * 16; idx += blockDim.x) {
    int k = idx >> 4, j = idx & 15;
    Wt[j * 516 + k] = W[idx];
  }
  __syncthreads();
  int wave = (blockIdx.x * blockDim.x + threadIdx.x) >> 6;
  int lane = threadIdx.x & 63;
  int r4 = lane >> 4, j = lane & 15;
  long row = (long)wave * 4 + r4;
  if (row >= N) return;
  const float4* X4 = (const float4*)(X + row * D_IN);
  const float4* w4 = (const float4*)(&Wt[j * 516]);
  float acc = 0.f;
#pragma unroll 8
  for (int kb = 0; kb < D_IN / 4; ++kb) {
    float4 x = X4[kb];
    float4 w = w4[kb];
    acc += x.x * w.x + x.y * w.y + x.z * w.z + x.w * w.w;
  }
  Hout[row * 16 + j] = acc;
  // epilogue: phv[row] = (h . a1, h . a2[:16]) via 16-lane group reduce
  float p1 = acc * a1[j];
  float p2 = acc * a2[j];
#pragma unroll
  for (int d = 1; d < 16; d <<= 1) { p1 += __shfl_xor(p1, d); p2 += __shfl_xor(p2, d); }
  if (j == 0) phv[row] = make_float2(p1, p2);
}

// ---------------- GEMM2: h2 = elu(H1)[100000,16] @ W2[16,7] (+ phv epilogue) ----------------
__global__ void gemm2_kernel(const float* __restrict__ H1, const float* __restrict__ W2,
                             const float* __restrict__ a1, const float* __restrict__ a2,
                             float* __restrict__ h2, float2* __restrict__ phv, int N) {
  __shared__ float w[D_HID * N_CLS];
  if (threadIdx.x < D_HID * N_CLS) w[threadIdx.x] = W2[threadIdx.x];
  __syncthreads();
  int v = blockIdx.x * blockDim.x + threadIdx.x;
  if (v >= N) return;
  const float4* h4 = (const float4*)(H1 + (size_t)v * D_HID);
  float x[16];
#pragma unroll
  for (int q = 0; q < 4; ++q) {
    float4 f = h4[q];
    x[q * 4 + 0] = f.x; x[q * 4 + 1] = f.y; x[q * 4 + 2] = f.z; x[q * 4 + 3] = f.w;
  }
#pragma unroll
  for (int k = 0; k < 16; ++k) x[k] = x[k] > 0.f ? x[k] : expm1f(x[k]);
  float p1 = 0.f, p2 = 0.f;
#pragma unroll
  for (int jj = 0; jj < N_CLS; ++jj) {
    float acc = 0.f;
#pragma unroll
    for (int k = 0; k < 16; ++k) acc += x[k] * w[k * N_CLS + jj];
    h2[(size_t)v * N_CLS + jj] = acc;
    p1 += acc * a1[jj];
    p2 += acc * a2[jj];
  }
  phv[v] = make_float2(p1, p2);
}

// ---------------- edge phase ----------------
// pass 1: 64 lanes = 64 entries in flight, online max+sum on scalar scores (phv.x, L2-resident)
// pass 2: GROUP-lane groups gather h rows ONCE with weight exp(s-m)
// epilogue: pe[edge] = eout . a2[D:2D]
template <int D, int GROUP>
__global__ void edge_phase(const float* __restrict__ h, const float2* __restrict__ phv,
                           const float* __restrict__ a2,
                           const int* __restrict__ eoff, const int* __restrict__ nidx,
                           float* __restrict__ eout, float* __restrict__ pe, int E) {
  constexpr int NG = 64 / GROUP;
  int wave = (blockIdx.x * blockDim.x + threadIdx.x) >> 6;
  int lane = threadIdx.x & 63;
  if (wave >= E) return;
  int o0 = eoff[wave], o1 = eoff[wave + 1];
  int g = lane / GROUP, t = lane % GROUP;
  if (o0 == o1) {
    if (g == 0 && t < D) eout[(size_t)wave * D + t] = 0.f;
    if (lane == 0) pe[wave] = 0.f;
    return;
  }
  // pass 1: online softmax stats, one entry per lane
  float m = -1e30f, l = 0.f;
  for (int i = o0 + lane; i < o1; i += 64) {
    float p = phv[nidx[i]].x;
    float s = p > 0.f ? p : 0.2f * p;
    float mn = fmaxf(m, s);
    l = l * __expf(m - mn) + __expf(s - mn);
    m = mn;
  }
#pragma unroll
  for (int d = 1; d < 64; d <<= 1) {
    float mo = __shfl_xor(m, d), lo = __shfl_xor(l, d);
    float mn = fmaxf(m, mo);
    l = l * __expf(m - mn) + lo * __expf(mo - mn);
    m = mn;
  }
  // pass 2: weighted accumulate of h rows (gathered once)
  float acc = 0.f;
  for (int i = o0 + g; i < o1; i += NG) {
    int v = nidx[i];
    float p = phv[v].x;
    float s = p > 0.f ? p : 0.2f * p;
    float ex = __expf(s - m);
    float hv = (t < D) ? h[(size_t)v * D + t] : 0.f;
    acc += ex * hv;
  }
#pragma unroll
  for (int d = GROUP; d < 64; d <<= 1) acc += __shfl_xor(acc, d);
  float val = acc / (l + 1e-9f);
  // epilogue: pe = val . a2[D:2D] (val identical across groups per t)
  float pa = (t < D) ? val * a2[D + t] : 0.f;
#pragma unroll
  for (int d = 1; d < GROUP; d <<= 1) pa += __shfl_xor(pa, d);
  if (g == 0) {
    if (t < D) eout[(size_t)wave * D + t] = val;
    if (t == 0) pe[wave] = pa;
  }
}

// ---------------- node phase ----------------
// pass 1: 64 entries in flight over perm_e + pe (both small/coalesced), online stats
// pass 2: GROUP-lane groups gather eout rows ONCE
template <int D, int GROUP>
__global__ void node_phase(const float2* __restrict__ phv, const float* __restrict__ eoutv,
                           const float* __restrict__ pe, const int* __restrict__ noff,
                           const int* __restrict__ perm_e, float* __restrict__ out, int N) {
  constexpr int NG = 64 / GROUP;
  int wave = (blockIdx.x * blockDim.x + threadIdx.x) >> 6;
  int lane = threadIdx.x & 63;
  if (wave >= N) return;
  int o0 = noff[wave], o1 = noff[wave + 1];
  int g = lane / GROUP, t = lane % GROUP;
  if (o0 == o1) {
    if (g == 0 && t < D) out[(size_t)wave * D + t] = 0.f;
    return;
  }
  float ph = phv[wave].y;
  float m = -1e30f, l = 0.f;
  for (int i = o0 + lane; i < o1; i += 64) {
    float p = ph + pe[perm_e[i]];
    float s = p > 0.f ? p : 0.2f * p;
    float mn = fmaxf(m, s);
    l = l * __expf(m - mn) + __expf(s - mn);
    m = mn;
  }
#pragma unroll
  for (int d = 1; d < 64; d <<= 1) {
    float mo = __shfl_xor(m, d), lo = __shfl_xor(l, d);
    float mn = fmaxf(m, mo);
    l = l * __expf(m - mn) + lo * __expf(mo - mn);
    m = mn;
  }
  float acc = 0.f;
  for (int i = o0 + g; i < o1; i += NG) {
    int e = perm_e[i];
    float p = ph + pe[e];
    float s = p > 0.f ? p : 0.2f * p;
    float ex = __expf(s - m);
    float ev = (t < D) ? eoutv[(size_t)e * D + t] : 0.f;
    acc += ex * ev;
  }
#pragma unroll
  for (int d = GROUP; d < 64; d <<= 1) acc += __shfl_xor(acc, d);
  if (g == 0 && t < D) out[(size_t)wave * D + t] = acc / (l + 1e-9f);
}

// ---------------- log_softmax over 7 classes ----------------
__global__ void logsm_kernel(const float* __restrict__ H2, float* __restrict__ logp, int N) {
  int v = blockIdx.x * blockDim.x + threadIdx.x;
  if (v >= N) return;
  float x[N_CLS];
#pragma unroll
  for (int j = 0; j < N_CLS; ++j) x[j] = H2[(size_t)v * N_CLS + j];
  float m = x[0];
#pragma unroll
  for (int j = 1; j < N_CLS; ++j) m = fmaxf(m, x[j]);
  float s = 0.f;
#pragma unroll
  for (int j = 0; j < N_CLS; ++j) s += __expf(x[j] - m);
  float l = logf(s);
#pragma unroll
  for (int j = 0; j < N_CLS; ++j) logp[(size_t)v * N_CLS + j] = x[j] - m - l;
}

// ---------------- launch ----------------

extern "C" void kernel_launch(void* const* d_in, const int* in_sizes, int n_in,
                              void* d_out, int out_size, void* d_ws, size_t ws_size,
                              hipStream_t stream) {
  const float* H    = (const float*)d_in[0];
  const float* W1   = (const float*)d_in[1];
  const float* a1_1 = (const float*)d_in[2];
  const float* a2_1 = (const float*)d_in[3];
  const float* W2   = (const float*)d_in[4];
  const float* a1_2 = (const float*)d_in[5];
  const float* a2_2 = (const float*)d_in[6];
  const int* nidx   = (const int*)d_in[7];
  const int* eidx   = (const int*)d_in[8];

  float* outp = (float*)d_out;
  float* logp = outp;                                   // [N,7]
  float* H1   = outp + (size_t)N_NODES * N_CLS;         // [N,16]
  float* H2   = H1 + (size_t)N_NODES * D_HID;           // [N,7]

  char* ws = (char*)d_ws;
  float* h1g  = (float*)(ws + 0);          //  6,400,000 B : N x 16
  float* e1   = (float*)(ws + 6400000);    //  6,400,000 B : E x 16
  float* h2g  = (float*)(ws + 12800000);   //  2,800,000 B : N x 7
  float* e2   = (float*)(ws + 15600000);   //  2,800,000 B : E x 7
  int* eoff   = (int*)(ws + 18400000);     //    400,004 B : E+1
  int* noff   = (int*)(ws + 18800128);     //    400,004 B : N+1
  int* ncnt   = (int*)(ws + 19200256);     //    400,000 B : N (reused as pe after CSR build)
  float* pe   = (float*)(ws + 19200256);   //    (same region; free after scatter)
  int* perm_e = (int*)(ws + 19600384);     // 12,800,000 B : NNZ (edge ids in node-CSR order)
  float2* phv = (float2*)(ws + 32400384);  //    800,000 B : N x {ph_a1, ph_a2}

  const int TB = 256;
  const int nnz_blocks = (NNZ_C + TB - 1) / TB;

  // CSR by node (built once, reused by both layers)
  hipMemsetAsync(ncnt, 0, N_NODES * sizeof(int), stream);
  count_kernel<<<nnz_blocks, TB, 0, stream>>>(nidx, ncnt, NNZ_C);
  eoff_kernel<<<nnz_blocks, TB, 0, stream>>>(eidx, eoff, NNZ_C, N_EDGESC);
  scan_kernel<<<1, 1024, 0, stream>>>(ncnt, noff, N_NODES);
  hipMemsetAsync(ncnt, 0, N_NODES * sizeof(int), stream);
  scatter_kernel<<<nnz_blocks, TB, 0, stream>>>(nidx, eidx, noff, ncnt, perm_e, NNZ_C);

  // layer 1 (D=16)
  {
    int waves = (N_NODES + 3) / 4;
    int blocks = (waves + 3) / 4;
    gemm1_kernel<<<blocks, TB, 0, stream>>>(H, W1, a1_1, a2_1, h1g, phv, N_NODES);
  }
  edge_phase<D_HID, 16><<<(N_EDGESC + 3) / 4, TB, 0, stream>>>(h1g, phv, a2_1, eoff, nidx, e1, pe, N_EDGESC);
  node_phase<D_HID, 16><<<(N_NODES + 3) / 4, TB, 0, stream>>>(phv, e1, pe, noff, perm_e, H1, N_NODES);

  // layer 2 (D=7)
  gemm2_kernel<<<(N_NODES + TB - 1) / TB, TB, 0, stream>>>(H1, W2, a1_2, a2_2, h2g, phv, N_NODES);
  edge_phase<N_CLS, 8><<<(N_EDGESC + 3) / 4, TB, 0, stream>>>(h2g, phv, a2_2, eoff, nidx, e2, pe, N_EDGESC);
  node_phase<N_CLS, 8><<<(N_NODES + 3) / 4, TB, 0, stream>>>(phv, e2, pe, noff, perm_e, H2, N_NODES);

  logsm_kernel<<<(N_NODES + TB - 1) / TB, TB, 0, stream>>>(H2, logp, N_NODES);
}

// Round 3
// 782.819 us; speedup vs baseline: 2.1103x; 1.6276x over previous
//
#include <hip/hip_runtime.h>
#include <hip/hip_bf16.h>
#include <math.h>

#define N_NODES 100000
#define N_EDGESC 100000
#define NNZ_C   3200000
#define D_IN    512
#define D_HID   16
#define N_CLS   7
#define NBK     782   // ceil(100000/128) node buckets, bucket = v>>7

// ---------------- setup: eoff from sorted eidx ----------------
__global__ void eoff_kernel(const int* __restrict__ eidx, int* __restrict__ eoff, int nnz, int E) {
  int i = blockIdx.x * blockDim.x + threadIdx.x;
  if (i >= nnz) return;
  int ec = eidx[i];
  int ep = (i == 0) ? -1 : eidx[i - 1];
  for (int e = ep + 1; e <= ec; ++e) eoff[e] = i;
  if (i == nnz - 1) {
    for (int e = ec + 1; e <= E; ++e) eoff[e] = nnz;
  }
}

// ---------------- setup: bucket histogram (LDS-staged) ----------------
__global__ void hist_kernel(const int* __restrict__ nidx, int* __restrict__ gcnt, int nnz) {
  __shared__ int lh[NBK];
  int t = threadIdx.x;
  for (int i = t; i < NBK; i += 256) lh[i] = 0;
  __syncthreads();
  int base = blockIdx.x * 12800;
  for (int it = 0; it < 50; ++it) {
    int i = base + it * 256 + t;
    if (i < nnz) atomicAdd(&lh[nidx[i] >> 7], 1);
  }
  __syncthreads();
  for (int i = t; i < NBK; i += 256) {
    int c = lh[i];
    if (c) atomicAdd(&gcnt[i], c);
  }
}

// ---------------- setup: scan bucket counts -> boff, init bcur ----------------
__global__ void bscan_kernel(const int* __restrict__ gcnt, int* __restrict__ boff,
                             int* __restrict__ bcur) {
  __shared__ int lds[1024];
  int t = threadIdx.x;
  int v = (t < NBK) ? gcnt[t] : 0;
  lds[t] = v;
  __syncthreads();
  for (int d = 1; d < 1024; d <<= 1) {
    int u = (t >= d) ? lds[t - d] : 0;
    __syncthreads();
    lds[t] += u;
    __syncthreads();
  }
  if (t < NBK) {
    boff[t + 1] = lds[t];
    bcur[t] = lds[t] - v;   // exclusive
  }
  if (t == 0) boff[0] = 0;
}

// ---------------- setup: bin entries (packed e | (v&127)<<20) per bucket ----------------
__global__ void bin_kernel(const int* __restrict__ nidx, const int* __restrict__ eidx,
                           int* __restrict__ bcur, int* __restrict__ binned, int nnz) {
  __shared__ int lh[NBK];
  __shared__ int gb[NBK];
  int t = threadIdx.x;
  for (int i = t; i < NBK; i += 256) lh[i] = 0;
  __syncthreads();
  int base = blockIdx.x * 12800;
  for (int it = 0; it < 50; ++it) {
    int i = base + it * 256 + t;
    if (i < nnz) atomicAdd(&lh[nidx[i] >> 7], 1);
  }
  __syncthreads();
  for (int i = t; i < NBK; i += 256) {
    int c = lh[i];
    gb[i] = c ? atomicAdd(&bcur[i], c) : 0;
    lh[i] = 0;
  }
  __syncthreads();
  for (int it = 0; it < 50; ++it) {
    int i = base + it * 256 + t;
    if (i < nnz) {
      int v = nidx[i], e = eidx[i];
      int bk = v >> 7;
      int r = atomicAdd(&lh[bk], 1);
      binned[gb[bk] + r] = e | ((v & 127) << 20);
    }
  }
}

// ---------------- setup: per-bucket node-CSR (noff + perm_e) ----------------
__global__ void csr_kernel(const int* __restrict__ binned, const int* __restrict__ boff,
                           int* __restrict__ noff, int* __restrict__ perm_e, int N) {
  __shared__ int lh[128];
  __shared__ int lsc[128];
  __shared__ int lcur[128];
  int b = blockIdx.x;
  int t = threadIdx.x;
  int s = boff[b], e = boff[b + 1];
  if (t < 128) lh[t] = 0;
  __syncthreads();
  for (int i = s + t; i < e; i += 256) {
    atomicAdd(&lh[binned[i] >> 20], 1);
  }
  __syncthreads();
  if (t < 128) lsc[t] = lh[t];
  __syncthreads();
  for (int d = 1; d < 128; d <<= 1) {
    int u = (t < 128 && t >= d) ? lsc[t - d] : 0;
    __syncthreads();
    if (t < 128) lsc[t] += u;
    __syncthreads();
  }
  if (t < 128) {
    int excl = lsc[t] - lh[t];
    lcur[t] = excl;
    int n = b * 128 + t;
    if (n <= N) noff[n] = s + excl;
  }
  __syncthreads();
  for (int i = s + t; i < e; i += 256) {
    int p = binned[i];
    int r = atomicAdd(&lcur[p >> 20], 1);
    perm_e[s + r] = p & 0xFFFFF;
  }
}

// ---------------- GEMM1: h = X[100000,512] @ W[512,16]  (+ phv epilogue) ----------------
// 1 wave per block, 64 rows x 16 cols; per-lane 4x4 register tile (nr=16 x nc=4 lanes).
// X staged in LDS in 32-k chunks (pitch 36 = conflict-minimal), W staged per chunk (2KB).
__global__ __launch_bounds__(64) void gemm1_kernel(
    const float* __restrict__ X, const float* __restrict__ W,
    const float* __restrict__ a1, const float* __restrict__ a2,
    float* __restrict__ Hout, float2* __restrict__ phv, int N) {
  __shared__ float Xs[64 * 36];
  __shared__ float Wc[32 * 16];
  int t = threadIdx.x;
  int rlane = t & 15, clane = t >> 4;   // 16 row-lanes x 4 col-lanes
  int rowbase = blockIdx.x * 64;
  float acc[4][4];
#pragma unroll
  for (int rr = 0; rr < 4; ++rr)
#pragma unroll
    for (int j = 0; j < 4; ++j) acc[rr][j] = 0.f;

  for (int kc = 0; kc < 512; kc += 32) {
    __syncthreads();
    // stage W chunk: 32 k x 16 j = 512 floats = 128 float4; 2 per thread
    {
      const float4* wsrc = (const float4*)(W + kc * 16);
      ((float4*)Wc)[t] = wsrc[t];
      ((float4*)Wc)[64 + t] = wsrc[64 + t];
    }
    // stage X: 64 rows x 32 floats (8 float4/row); 512 f4 / 64 thr = 8 iters
    for (int it = 0; it < 8; ++it) {
      int idx = it * 64 + t;
      int r = idx >> 3, f = idx & 7;
      int grow = rowbase + r;
      float4 val = make_float4(0.f, 0.f, 0.f, 0.f);
      if (grow < N) val = *(const float4*)(X + (size_t)grow * D_IN + kc + f * 4);
      *(float4*)(Xs + r * 36 + f * 4) = val;
    }
    __syncthreads();
#pragma unroll
    for (int kb = 0; kb < 8; ++kb) {
      float xv[4][4];
#pragma unroll
      for (int rr = 0; rr < 4; ++rr) {
        float4 xr = *(const float4*)(Xs + (rr * 16 + rlane) * 36 + kb * 4);
        xv[rr][0] = xr.x; xv[rr][1] = xr.y; xv[rr][2] = xr.z; xv[rr][3] = xr.w;
      }
#pragma unroll
      for (int kk = 0; kk < 4; ++kk) {
        float4 wv = *(const float4*)(Wc + (kb * 4 + kk) * 16 + clane * 4);
#pragma unroll
        for (int rr = 0; rr < 4; ++rr) {
          acc[rr][0] += xv[rr][kk] * wv.x;
          acc[rr][1] += xv[rr][kk] * wv.y;
          acc[rr][2] += xv[rr][kk] * wv.z;
          acc[rr][3] += xv[rr][kk] * wv.w;
        }
      }
    }
  }
  // epilogue: store H rows + fused phv = (h.a1, h.a2[:16])
  float a1v[4], a2v[4];
#pragma unroll
  for (int j = 0; j < 4; ++j) { a1v[j] = a1[clane * 4 + j]; a2v[j] = a2[clane * 4 + j]; }
#pragma unroll
  for (int rr = 0; rr < 4; ++rr) {
    int grow = rowbase + rr * 16 + rlane;
    if (grow < N) {
      *(float4*)(Hout + (size_t)grow * 16 + clane * 4) =
          make_float4(acc[rr][0], acc[rr][1], acc[rr][2], acc[rr][3]);
    }
    float p1 = acc[rr][0] * a1v[0] + acc[rr][1] * a1v[1] + acc[rr][2] * a1v[2] + acc[rr][3] * a1v[3];
    float p2 = acc[rr][0] * a2v[0] + acc[rr][1] * a2v[1] + acc[rr][2] * a2v[2] + acc[rr][3] * a2v[3];
    p1 += __shfl_xor(p1, 16); p1 += __shfl_xor(p1, 32);
    p2 += __shfl_xor(p2, 16); p2 += __shfl_xor(p2, 32);
    if (clane == 0 && grow < N) phv[grow] = make_float2(p1, p2);
  }
}

// ---------------- GEMM2: h2 = elu(H1)[100000,16] @ W2[16,7] (+ phv epilogue) ----------------
__global__ void gemm2_kernel(const float* __restrict__ H1, const float* __restrict__ W2,
                             const float* __restrict__ a1, const float* __restrict__ a2,
                             float* __restrict__ h2, float2* __restrict__ phv, int N) {
  __shared__ float w[D_HID * N_CLS];
  if (threadIdx.x < D_HID * N_CLS) w[threadIdx.x] = W2[threadIdx.x];
  __syncthreads();
  int v = blockIdx.x * blockDim.x + threadIdx.x;
  if (v >= N) return;
  const float4* h4 = (const float4*)(H1 + (size_t)v * D_HID);
  float x[16];
#pragma unroll
  for (int q = 0; q < 4; ++q) {
    float4 f = h4[q];
    x[q * 4 + 0] = f.x; x[q * 4 + 1] = f.y; x[q * 4 + 2] = f.z; x[q * 4 + 3] = f.w;
  }
#pragma unroll
  for (int k = 0; k < 16; ++k) x[k] = x[k] > 0.f ? x[k] : expm1f(x[k]);
  float p1 = 0.f, p2 = 0.f;
#pragma unroll
  for (int jj = 0; jj < N_CLS; ++jj) {
    float acc = 0.f;
#pragma unroll
    for (int k = 0; k < 16; ++k) acc += x[k] * w[k * N_CLS + jj];
    h2[(size_t)v * N_CLS + jj] = acc;
    p1 += acc * a1[jj];
    p2 += acc * a2[jj];
  }
  phv[v] = make_float2(p1, p2);
}

// ---------------- edge phase ----------------
template <int D, int GROUP>
__global__ void edge_phase(const float* __restrict__ h, const float2* __restrict__ phv,
                           const float* __restrict__ a2,
                           const int* __restrict__ eoff, const int* __restrict__ nidx,
                           float* __restrict__ eout, float* __restrict__ pe, int E) {
  constexpr int NG = 64 / GROUP;
  int wave = (blockIdx.x * blockDim.x + threadIdx.x) >> 6;
  int lane = threadIdx.x & 63;
  if (wave >= E) return;
  int o0 = eoff[wave], o1 = eoff[wave + 1];
  int g = lane / GROUP, t = lane % GROUP;
  if (o0 == o1) {
    if (g == 0 && t < D) eout[(size_t)wave * D + t] = 0.f;
    if (lane == 0) pe[wave] = 0.f;
    return;
  }
  float m = -1e30f, l = 0.f;
  for (int i = o0 + lane; i < o1; i += 64) {
    float p = phv[nidx[i]].x;
    float s = p > 0.f ? p : 0.2f * p;
    float mn = fmaxf(m, s);
    l = l * __expf(m - mn) + __expf(s - mn);
    m = mn;
  }
#pragma unroll
  for (int d = 1; d < 64; d <<= 1) {
    float mo = __shfl_xor(m, d), lo = __shfl_xor(l, d);
    float mn = fmaxf(m, mo);
    l = l * __expf(m - mn) + lo * __expf(mo - mn);
    m = mn;
  }
  float acc = 0.f;
  for (int i = o0 + g; i < o1; i += NG) {
    int v = nidx[i];
    float p = phv[v].x;
    float s = p > 0.f ? p : 0.2f * p;
    float ex = __expf(s - m);
    float hv = (t < D) ? h[(size_t)v * D + t] : 0.f;
    acc += ex * hv;
  }
#pragma unroll
  for (int d = GROUP; d < 64; d <<= 1) acc += __shfl_xor(acc, d);
  float val = acc / (l + 1e-9f);
  float pa = (t < D) ? val * a2[D + t] : 0.f;
#pragma unroll
  for (int d = 1; d < GROUP; d <<= 1) pa += __shfl_xor(pa, d);
  if (g == 0) {
    if (t < D) eout[(size_t)wave * D + t] = val;
    if (t == 0) pe[wave] = pa;
  }
}

// ---------------- node phase ----------------
template <int D, int GROUP>
__global__ void node_phase(const float2* __restrict__ phv, const float* __restrict__ eoutv,
                           const float* __restrict__ pe, const int* __restrict__ noff,
                           const int* __restrict__ perm_e, float* __restrict__ out, int N) {
  constexpr int NG = 64 / GROUP;
  int wave = (blockIdx.x * blockDim.x + threadIdx.x) >> 6;
  int lane = threadIdx.x & 63;
  if (wave >= N) return;
  int o0 = noff[wave], o1 = noff[wave + 1];
  int g = lane / GROUP, t = lane % GROUP;
  if (o0 == o1) {
    if (g == 0 && t < D) out[(size_t)wave * D + t] = 0.f;
    return;
  }
  float ph = phv[wave].y;
  float m = -1e30f, l = 0.f;
  for (int i = o0 + lane; i < o1; i += 64) {
    float p = ph + pe[perm_e[i]];
    float s = p > 0.f ? p : 0.2f * p;
    float mn = fmaxf(m, s);
    l = l * __expf(m - mn) + __expf(s - mn);
    m = mn;
  }
#pragma unroll
  for (int d = 1; d < 64; d <<= 1) {
    float mo = __shfl_xor(m, d), lo = __shfl_xor(l, d);
    float mn = fmaxf(m, mo);
    l = l * __expf(m - mn) + lo * __expf(mo - mn);
    m = mn;
  }
  float acc = 0.f;
  for (int i = o0 + g; i < o1; i += NG) {
    int e = perm_e[i];
    float p = ph + pe[e];
    float s = p > 0.f ? p : 0.2f * p;
    float ex = __expf(s - m);
    float ev = (t < D) ? eoutv[(size_t)e * D + t] : 0.f;
    acc += ex * ev;
  }
#pragma unroll
  for (int d = GROUP; d < 64; d <<= 1) acc += __shfl_xor(acc, d);
  if (g == 0 && t < D) out[(size_t)wave * D + t] = acc / (l + 1e-9f);
}

// ---------------- log_softmax over 7 classes ----------------
__global__ void logsm_kernel(const float* __restrict__ H2, float* __restrict__ logp, int N) {
  int v = blockIdx.x * blockDim.x + threadIdx.x;
  if (v >= N) return;
  float x[N_CLS];
#pragma unroll
  for (int j = 0; j < N_CLS; ++j) x[j] = H2[(size_t)v * N_CLS + j];
  float m = x[0];
#pragma unroll
  for (int j = 1; j < N_CLS; ++j) m = fmaxf(m, x[j]);
  float s = 0.f;
#pragma unroll
  for (int j = 0; j < N_CLS; ++j) s += __expf(x[j] - m);
  float l = logf(s);
#pragma unroll
  for (int j = 0; j < N_CLS; ++j) logp[(size_t)v * N_CLS + j] = x[j] - m - l;
}

// ---------------- launch ----------------

extern "C" void kernel_launch(void* const* d_in, const int* in_sizes, int n_in,
                              void* d_out, int out_size, void* d_ws, size_t ws_size,
                              hipStream_t stream) {
  const float* H    = (const float*)d_in[0];
  const float* W1   = (const float*)d_in[1];
  const float* a1_1 = (const float*)d_in[2];
  const float* a2_1 = (const float*)d_in[3];
  const float* W2   = (const float*)d_in[4];
  const float* a1_2 = (const float*)d_in[5];
  const float* a2_2 = (const float*)d_in[6];
  const int* nidx   = (const int*)d_in[7];
  const int* eidx   = (const int*)d_in[8];

  float* outp = (float*)d_out;
  float* logp = outp;                                   // [N,7]
  float* H1   = outp + (size_t)N_NODES * N_CLS;         // [N,16]
  float* H2   = H1 + (size_t)N_NODES * D_HID;           // [N,7]

  char* ws = (char*)d_ws;
  // binned (12.8 MB) aliases h1g+e1: dead before gemm1 writes h1g.
  int*   binned = (int*)(ws + 0);
  float* h1g  = (float*)(ws + 0);          //  6,400,000 B : N x 16
  float* e1   = (float*)(ws + 6400000);    //  6,400,000 B : E x 16
  float* h2g  = (float*)(ws + 12800000);   //  2,800,000 B : N x 7
  float* e2   = (float*)(ws + 15600000);   //  2,800,000 B : E x 7
  int* eoff   = (int*)(ws + 18400000);     //    400,004 B : E+1
  int* noff   = (int*)(ws + 18800128);     //    400,004 B : N+1
  float* pe   = (float*)(ws + 19200256);   //    400,000 B : E
  int* perm_e = (int*)(ws + 19600384);     // 12,800,000 B : NNZ (edge ids, node-CSR order)
  float2* phv = (float2*)(ws + 32400384);  //    800,000 B : N x {p_a1, p_a2}
  int* gcnt   = (int*)(ws + 33200384);     //      3,128 B : NBK
  int* boff   = (int*)(ws + 33203584);     //      3,132 B : NBK+1
  int* bcur   = (int*)(ws + 33206784);     //      3,128 B : NBK

  const int TB = 256;
  const int nnz_blocks = (NNZ_C + TB - 1) / TB;

  // CSR build (two-level binning; no global scan, no random-line scatter)
  hipMemsetAsync(gcnt, 0, NBK * sizeof(int), stream);
  eoff_kernel<<<nnz_blocks, TB, 0, stream>>>(eidx, eoff, NNZ_C, N_EDGESC);
  hist_kernel<<<250, TB, 0, stream>>>(nidx, gcnt, NNZ_C);
  bscan_kernel<<<1, 1024, 0, stream>>>(gcnt, boff, bcur);
  bin_kernel<<<250, TB, 0, stream>>>(nidx, eidx, bcur, binned, NNZ_C);
  csr_kernel<<<NBK, TB, 0, stream>>>(binned, boff, noff, perm_e, N_NODES);

  // layer 1 (D=16)
  gemm1_kernel<<<(N_NODES + 63) / 64, 64, 0, stream>>>(H, W1, a1_1, a2_1, h1g, phv, N_NODES);
  edge_phase<D_HID, 16><<<(N_EDGESC + 3) / 4, TB, 0, stream>>>(h1g, phv, a2_1, eoff, nidx, e1, pe, N_EDGESC);
  node_phase<D_HID, 16><<<(N_NODES + 3) / 4, TB, 0, stream>>>(phv, e1, pe, noff, perm_e, H1, N_NODES);

  // layer 2 (D=7)
  gemm2_kernel<<<(N_NODES + TB - 1) / TB, TB, 0, stream>>>(H1, W2, a1_2, a2_2, h2g, phv, N_NODES);
  edge_phase<N_CLS, 8><<<(N_EDGESC + 3) / 4, TB, 0, stream>>>(h2g, phv, a2_2, eoff, nidx, e2, pe, N_EDGESC);
  node_phase<N_CLS, 8><<<(N_NODES + 3) / 4, TB, 0, stream>>>(phv, e2, pe, noff, perm_e, H2, N_NODES);

  logsm_kernel<<<(N_NODES + TB - 1) / TB, TB, 0, stream>>>(H2, logp, N_NODES);
}